// Round 10
// baseline (136.832 us; speedup 1.0000x reference)
//
#include <hip/hip_runtime.h>

// x: [128,8,32,32,32] f32  cw: [16,8,3,3,3] f32  cb: [16]  bias: [16]  out: [128]
// out[b] = (1/6750)*sum_{c,cells} maxpool2(conv_raw) + sum_c(cb[c]/2 + bias[c])
//
// R10 = R7 verbatim with the pd-walk split in half: block = (b, h-eighth q,
// pd-half). Grid 2048 = 8 blocks/CU (launch_bounds(256,8) pins VGPR<=64; R9
// proved 64 feasible with more live state). Only planes 16,17 double-fetched.
// Compute body verified R3/R5/R7 (absmax 0.125).

using short8 = __attribute__((ext_vector_type(8))) short;
using f32x4  = __attribute__((ext_vector_type(4))) float;

__device__ __forceinline__ unsigned short f2bf_rn(float f) {
  unsigned u = __float_as_uint(f);
  return (unsigned short)((u + 0x7FFFu + ((u >> 16) & 1u)) >> 16);
}

// Bp[g=kd*3+kh][lane]: 8 bf16 = w[co=lane&15][ci=j][kd][kh][kw=lane>>4]; kw==3 -> 0
__global__ __launch_bounds__(256) void prep_w(const float* __restrict__ cw,
                                              short* __restrict__ Bp) {
  int i = threadIdx.x + blockIdx.x * 256;
  if (i >= 576) return;
  int g = i >> 6, l = i & 63;
  int co = l & 15, kw = l >> 4;
  int kd = g / 3, kh = g % 3;
  short8 o;
#pragma unroll
  for (int j = 0; j < 8; ++j) {
    float v = (kw < 3) ? cw[(co * 8 + j) * 27 + kd * 9 + kh * 3 + kw] : 0.0f;
    o[j] = (short)f2bf_rn(v);
  }
  *(short8*)(Bp + (size_t)i * 8) = o;
}

__global__ __launch_bounds__(256, 8) void conv_mfma(const float* __restrict__ x,
                                                    const short* __restrict__ Bp,
                                                    float* __restrict__ partial) {
  __shared__ __align__(16) char lds[6 * 3072];  // 6-slab ring; slab=[r6][w32][ci8] bf16
  __shared__ float red[4];

  const int bid = blockIdx.x;                    // 2048 blocks = 8/CU exactly
  const int swz = (bid & 7) * 256 + (bid >> 3);  // XCD-chunk, bijective
  const int b = swz >> 4;                        // 16 consecutive b per XCD
  const int q = (swz >> 1) & 7;                  // oh rows 4q..4q+3 (q=7: 2 rows)
  const int half = swz & 1;                      // pd 0..7 / 8..14
  const int t = threadIdx.x, lane = t & 63, wv = t >> 6;
  const int nrows = (q == 7) ? 4 : 6;
  const int row0 = 4 * q;
  const int sites = nrows * 16;
  const int pbase = half ? 16 : 0;               // global plane = pbase + lp
  const int nsteps = half ? 7 : 8;
  const float* xb = x + (size_t)b * 262144;

  // ---- staging decode: site = (plane-of-pair spl, local row sr, w-group swg) ----
  const bool sact = t < 2 * sites;
  const int spl = (t >= sites) ? 1 : 0;
  const int ss = sact ? (t - spl * sites) : 0;
  const int sr = ss >> 4, swg = ss & 15;
  const float* gsite = xb + (row0 + sr) * 32 + swg * 2;  // + plane*1024 + ci*32768

  auto issueB = [&](int lp, float2* v) {  // lp = local plane base (even)
    if (!sact) return;
    const float* gp = gsite + (pbase + lp + spl) * 1024;
#pragma unroll
    for (int ci = 0; ci < 8; ++ci) v[ci] = *(const float2*)(gp + ci * 32768);
  };
  auto writeB = [&](int lp, const float2* v) {  // slot = (lp+spl) % 6
    if (!sact) return;
    char* sb = lds + ((lp + spl) % 6) * 3072 + sr * 512;
#pragma unroll
    for (int wi = 0; wi < 2; ++wi) {
      const int w = swg * 2 + wi;
      uint4 o;  // truncation bf16 pack [ci0..ci7] (verified R6/R7)
      o.x = __builtin_amdgcn_perm(__float_as_uint(((const float*)&v[1])[wi]),
                                  __float_as_uint(((const float*)&v[0])[wi]), 0x07060302u);
      o.y = __builtin_amdgcn_perm(__float_as_uint(((const float*)&v[3])[wi]),
                                  __float_as_uint(((const float*)&v[2])[wi]), 0x07060302u);
      o.z = __builtin_amdgcn_perm(__float_as_uint(((const float*)&v[5])[wi]),
                                  __float_as_uint(((const float*)&v[4])[wi]), 0x07060302u);
      o.w = __builtin_amdgcn_perm(__float_as_uint(((const float*)&v[7])[wi]),
                                  __float_as_uint(((const float*)&v[6])[wi]), 0x07060302u);
      *(uint4*)(sb + ((w * 16) ^ (((w >> 3) & 3) << 4))) = o;
    }
  };

  // ---- B fragments (9 (kd,kh) groups, block-invariant) ----
  short8 Bw[9];
#pragma unroll
  for (int g = 0; g < 9; ++g)
    Bw[g] = *(const short8*)(Bp + ((size_t)g * 64 + lane) * 8);

  // ---- per-lane A addressing (verified R3/R7) ----
  const int m = lane & 15, tg = lane >> 4;
  const int w0 = m + tg;
  int w1 = m + 16 + tg; if (w1 > 31) w1 = 31;  // clamp hits only masked/pad lanes
  const int wb0 = (w0 * 16) ^ (((w0 >> 3) & 3) << 4);
  const int wb1 = (w1 * 16) ^ (((w1 >> 3) & 3) << 4);

  const bool docomp = (q < 7) || (wv < 2);
  const int op = (q < 7) ? (wv >> 1) : 0;
  const int c  = (q < 7) ? (wv & 1) : wv;
  const int wbase = (c ? wb1 : wb0) + (2 * op) * 512;

  // ---- prologue: stage local planes 0..3 ----
  {
    float2 va[8], vb[8];
    issueB(0, va);
    issueB(2, vb);
    writeB(0, va);
    writeB(2, vb);
  }
  __syncthreads();

  // ---- main loop over local pd steps: issue -> compute -> write -> barrier ----
  float sum = 0.0f;
  int rs0 = 0;  // read slab base = (2*st)%6
  for (int st = 0; st < nsteps; ++st) {
    const bool more = (st < nsteps - 1);
    float2 va[8];
    if (more) issueB(2 * st + 4, va);  // issue BEFORE compute: latency cover

    if (docomp) {
      int sl1 = rs0 + 1;
      int sl2 = rs0 + 2; if (sl2 >= 6) sl2 -= 6;
      int sl3 = rs0 + 3; if (sl3 >= 6) sl3 -= 6;
      const char* sbp[4] = {lds + rs0 * 3072 + wbase, lds + sl1 * 3072 + wbase,
                            lds + sl2 * 3072 + wbase, lds + sl3 * 3072 + wbase};
      f32x4 cc[2][2] = {};  // [od][s]
#pragma unroll
      for (int p = 0; p < 4; ++p) {
#pragma unroll
        for (int rr = 0; rr < 4; ++rr) {
          const short8 a = *(const short8*)(sbp[p] + rr * 512);
          if (p < 3 && rr < 3)
            cc[0][0] = __builtin_amdgcn_mfma_f32_16x16x32_bf16(a, Bw[p * 3 + rr], cc[0][0], 0, 0, 0);
          if (p < 3 && rr > 0)
            cc[0][1] = __builtin_amdgcn_mfma_f32_16x16x32_bf16(a, Bw[p * 3 + rr - 1], cc[0][1], 0, 0, 0);
          if (p > 0 && rr < 3)
            cc[1][0] = __builtin_amdgcn_mfma_f32_16x16x32_bf16(a, Bw[(p - 1) * 3 + rr], cc[1][0], 0, 0, 0);
          if (p > 0 && rr > 0)
            cc[1][1] = __builtin_amdgcn_mfma_f32_16x16x32_bf16(a, Bw[(p - 1) * 3 + rr - 1], cc[1][1], 0, 0, 0);
        }
      }
      // maxpool 2x2x2 fully in-lane; mask pw 15 (ow 30/31) of chunk1
#pragma unroll
      for (int p2 = 0; p2 < 2; ++p2) {
        float v = fmaxf(fmaxf(fmaxf(cc[0][0][2 * p2], cc[0][0][2 * p2 + 1]),
                              fmaxf(cc[0][1][2 * p2], cc[0][1][2 * p2 + 1])),
                        fmaxf(fmaxf(cc[1][0][2 * p2], cc[1][0][2 * p2 + 1]),
                              fmaxf(cc[1][1][2 * p2], cc[1][1][2 * p2 + 1])));
        const bool inval = (c == 1) && (tg == 3) && (p2 == 1);
        sum += inval ? 0.0f : v;
      }
    }

    if (more) writeB(2 * st + 4, va);  // vmcnt wait + pack + ring write
    __syncthreads();
    rs0 += 2; if (rs0 >= 6) rs0 -= 6;
  }

  // ---- block reduction ----
#pragma unroll
  for (int off = 32; off; off >>= 1) sum += __shfl_down(sum, off);
  if (lane == 0) red[wv] = sum;
  __syncthreads();
  if (t == 0) partial[b * 16 + q * 2 + half] = red[0] + red[1] + red[2] + red[3];
}

__global__ __launch_bounds__(128) void finalize(const float* __restrict__ partial,
                                                const float* __restrict__ cb,
                                                const float* __restrict__ bias,
                                                float* __restrict__ out) {
  const int b = threadIdx.x;  // 128 threads, 1 block
  float k = 0.0f;
#pragma unroll
  for (int c = 0; c < 16; ++c) k += cb[c] * 0.5f + bias[c];
  float s = 0.0f;
#pragma unroll
  for (int i = 0; i < 16; ++i) s += partial[b * 16 + i];
  out[b] = s * (1.0f / 6750.0f) + k;
}

extern "C" void kernel_launch(void* const* d_in, const int* in_sizes, int n_in,
                              void* d_out, int out_size, void* d_ws, size_t ws_size,
                              hipStream_t stream) {
  const float* x    = (const float*)d_in[0];
  const float* cw   = (const float*)d_in[1];
  const float* cb   = (const float*)d_in[2];
  const float* bias = (const float*)d_in[3];
  float* out = (float*)d_out;

  short* Bp      = (short*)d_ws;                   // 576*16 B = 9216 B
  float* partial = (float*)((char*)d_ws + 32768);  // 2048 floats

  prep_w<<<3, 256, 0, stream>>>(cw, Bp);
  conv_mfma<<<2048, 256, 0, stream>>>(x, Bp, partial);
  finalize<<<1, 128, 0, stream>>>(partial, cb, bias, out);
}

// Round 11
// 54.297 us; speedup vs baseline: 2.5201x; 2.5201x over previous
//
#include <hip/hip_runtime.h>

// x: [128,8,32,32,32] f32  cw: [16,8,3,3,3] f32  cb: [16]  bias: [16]  out: [128]
// out[b] = (1/6750)*sum_{c,cells} maxpool2(conv_raw) + sum_c(cb[c]/2 + bias[c])
//
// R11 = R7 (best, 42.2us) + cross-step FRAGMENT PERSISTENCE: planes 2pd+2/2pd+3
// row-fragments stay in registers and serve as planes 2pd/2pd+1 next step.
// Steady-state ds_read_b128: 16 -> 8 per wave-step. Static even/odd register
// sets (no runtime-indexed arrays -> no scratch). Everything else R7-identical.

using short8 = __attribute__((ext_vector_type(8))) short;
using f32x4  = __attribute__((ext_vector_type(4))) float;

__device__ __forceinline__ unsigned short f2bf_rn(float f) {
  unsigned u = __float_as_uint(f);
  return (unsigned short)((u + 0x7FFFu + ((u >> 16) & 1u)) >> 16);
}

// Bp[g=kd*3+kh][lane]: 8 bf16 = w[co=lane&15][ci=j][kd][kh][kw=lane>>4]; kw==3 -> 0
__global__ __launch_bounds__(256) void prep_w(const float* __restrict__ cw,
                                              short* __restrict__ Bp) {
  int i = threadIdx.x + blockIdx.x * 256;
  if (i >= 576) return;
  int g = i >> 6, l = i & 63;
  int co = l & 15, kw = l >> 4;
  int kd = g / 3, kh = g % 3;
  short8 o;
#pragma unroll
  for (int j = 0; j < 8; ++j) {
    float v = (kw < 3) ? cw[(co * 8 + j) * 27 + kd * 9 + kh * 3 + kw] : 0.0f;
    o[j] = (short)f2bf_rn(v);
  }
  *(short8*)(Bp + (size_t)i * 8) = o;
}

__global__ __launch_bounds__(256, 4) void conv_mfma(const float* __restrict__ x,
                                                    const short* __restrict__ Bp,
                                                    float* __restrict__ partial) {
  __shared__ __align__(16) char lds[6 * 3072];  // 6-slab ring; slab=[r6][w32][ci8] bf16
  __shared__ float red[4];

  const int bid = blockIdx.x;                    // 1024 blocks = 4/CU
  const int swz = (bid & 7) * 128 + (bid >> 3);  // XCD-chunk, bijective
  const int b = swz >> 3, q = swz & 7;           // q: oh rows 4q..4q+3 (q=7: 2 rows)
  const int t = threadIdx.x, lane = t & 63, wv = t >> 6;
  const int nrows = (q == 7) ? 4 : 6;
  const int row0 = 4 * q;
  const int sites = nrows * 16;
  const float* xb = x + (size_t)b * 262144;

  // ---- staging decode (R7-identical) ----
  const bool sact = t < 2 * sites;
  const int spl = (t >= sites) ? 1 : 0;
  const int ss = sact ? (t - spl * sites) : 0;
  const int sr = ss >> 4, swg = ss & 15;
  const float* gsite = xb + (row0 + sr) * 32 + swg * 2;  // + plane*1024 + ci*32768

  auto issueB = [&](int pb, float2* v) {  // pb = plane base (even)
    if (!sact) return;
    const float* gp = gsite + (pb + spl) * 1024;
#pragma unroll
    for (int ci = 0; ci < 8; ++ci) v[ci] = *(const float2*)(gp + ci * 32768);
  };
  auto writeB = [&](int pb, const float2* v) {  // slot = (pb+spl) % 6
    if (!sact) return;
    char* sb = lds + ((pb + spl) % 6) * 3072 + sr * 512;
#pragma unroll
    for (int wi = 0; wi < 2; ++wi) {
      const int w = swg * 2 + wi;
      uint4 o;  // truncation bf16 pack [ci0..ci7] (verified R6/R7)
      o.x = __builtin_amdgcn_perm(__float_as_uint(((const float*)&v[1])[wi]),
                                  __float_as_uint(((const float*)&v[0])[wi]), 0x07060302u);
      o.y = __builtin_amdgcn_perm(__float_as_uint(((const float*)&v[3])[wi]),
                                  __float_as_uint(((const float*)&v[2])[wi]), 0x07060302u);
      o.z = __builtin_amdgcn_perm(__float_as_uint(((const float*)&v[5])[wi]),
                                  __float_as_uint(((const float*)&v[4])[wi]), 0x07060302u);
      o.w = __builtin_amdgcn_perm(__float_as_uint(((const float*)&v[7])[wi]),
                                  __float_as_uint(((const float*)&v[6])[wi]), 0x07060302u);
      *(uint4*)(sb + ((w * 16) ^ (((w >> 3) & 3) << 4))) = o;
    }
  };

  // ---- B fragments (9 (kd,kh) groups, block-invariant) ----
  short8 Bw[9];
#pragma unroll
  for (int g = 0; g < 9; ++g)
    Bw[g] = *(const short8*)(Bp + ((size_t)g * 64 + lane) * 8);

  // ---- per-lane A addressing (verified R3/R7) ----
  const int m = lane & 15, tg = lane >> 4;
  const int w0 = m + tg;
  int w1 = m + 16 + tg; if (w1 > 31) w1 = 31;  // clamp hits only masked/pad lanes
  const int wb0 = (w0 * 16) ^ (((w0 >> 3) & 3) << 4);
  const int wb1 = (w1 * 16) ^ (((w1 >> 3) & 3) << 4);

  const bool docomp = (q < 7) || (wv < 2);
  const int op = (q < 7) ? (wv >> 1) : 0;
  const int c  = (q < 7) ? (wv & 1) : wv;
  const int wbase = (c ? wb1 : wb0) + (2 * op) * 512;

  float sum = 0.0f;

  auto read4 = [&](int slot, short8 (&f)[4]) {
#pragma unroll
    for (int rr = 0; rr < 4; ++rr)
      f[rr] = *(const short8*)(lds + slot * 3072 + wbase + rr * 512);
  };
  auto mfma_p = [&](const short8 (&f)[4], int p, f32x4 (&cc)[2][2]) {
#pragma unroll
    for (int rr = 0; rr < 4; ++rr) {
      const short8 a = f[rr];
      if (p < 3 && rr < 3)
        cc[0][0] = __builtin_amdgcn_mfma_f32_16x16x32_bf16(a, Bw[p * 3 + rr], cc[0][0], 0, 0, 0);
      if (p < 3 && rr > 0)
        cc[0][1] = __builtin_amdgcn_mfma_f32_16x16x32_bf16(a, Bw[p * 3 + rr - 1], cc[0][1], 0, 0, 0);
      if (p > 0 && rr < 3)
        cc[1][0] = __builtin_amdgcn_mfma_f32_16x16x32_bf16(a, Bw[(p - 1) * 3 + rr], cc[1][0], 0, 0, 0);
      if (p > 0 && rr > 0)
        cc[1][1] = __builtin_amdgcn_mfma_f32_16x16x32_bf16(a, Bw[(p - 1) * 3 + rr - 1], cc[1][1], 0, 0, 0);
    }
  };
  auto pool = [&](f32x4 (&cc)[2][2]) {
#pragma unroll
    for (int p2 = 0; p2 < 2; ++p2) {
      float v = fmaxf(fmaxf(fmaxf(cc[0][0][2 * p2], cc[0][0][2 * p2 + 1]),
                            fmaxf(cc[0][1][2 * p2], cc[0][1][2 * p2 + 1])),
                      fmaxf(fmaxf(cc[1][0][2 * p2], cc[1][0][2 * p2 + 1]),
                            fmaxf(cc[1][1][2 * p2], cc[1][1][2 * p2 + 1])));
      const bool inval = (c == 1) && (tg == 3) && (p2 == 1);  // pw 15 invalid
      sum += inval ? 0.0f : v;
    }
  };

  // ---- prologue: stage planes 0..3 ----
  {
    float2 va[8], vb[8];
    issueB(0, va); issueB(2, vb);
    writeB(0, va); writeB(2, vb);
  }
  __syncthreads();

  // ---- step 0 (peeled): read all 16 frags; persist planes 2,3 into pA/pB ----
  short8 pA[4], pB[4], qA[4], qB[4];
  {
    float2 va[8];
    issueB(4, va);
    if (docomp) {
      short8 f0[4], f1[4];
      read4(0, f0);
      read4(1, f1);
      read4(2, pA);
      read4(3, pB);
      f32x4 cc[2][2] = {};
      mfma_p(f0, 0, cc);
      mfma_p(f1, 1, cc);
      mfma_p(pA, 2, cc);
      mfma_p(pB, 3, cc);
      pool(cc);
    }
    writeB(4, va);
    __syncthreads();
  }

  // ---- steps 1..14: 7 static double-steps (old set alternates pA/pB <-> qA/qB) ----
  int sl2 = 4, sl3 = 5;  // slots of planes 2st+2, 2st+3 (st=1: planes 4,5)
  auto step = [&](int st, short8 (&oldA)[4], short8 (&oldB)[4],
                  short8 (&nA)[4], short8 (&nB)[4]) {
    const bool more = st < 14;
    float2 va[8];
    if (more) issueB(2 * st + 4, va);  // issue BEFORE compute: latency cover
    if (docomp) {
      f32x4 cc[2][2] = {};
      read4(sl2, nA);          // LDS pipe runs while MFMA chews old frags
      mfma_p(oldA, 0, cc);     // oldA dies here
      mfma_p(oldB, 1, cc);     // oldB dies here
      read4(sl3, nB);
      mfma_p(nA, 2, cc);
      mfma_p(nB, 3, cc);
      pool(cc);
    }
    if (more) writeB(2 * st + 4, va);  // vmcnt wait + pack + ring write
    __syncthreads();
    sl2 += 2; if (sl2 >= 6) sl2 -= 6;
    sl3 += 2; if (sl3 >= 6) sl3 -= 6;
  };
#pragma unroll 1
  for (int dp = 0; dp < 7; ++dp) {
    step(2 * dp + 1, pA, pB, qA, qB);
    step(2 * dp + 2, qA, qB, pA, pB);
  }

  // ---- block reduction ----
#pragma unroll
  for (int off = 32; off; off >>= 1) sum += __shfl_down(sum, off);
  if (lane == 0) red[wv] = sum;
  __syncthreads();
  if (t == 0) partial[b * 8 + q] = red[0] + red[1] + red[2] + red[3];
}

__global__ __launch_bounds__(128) void finalize(const float* __restrict__ partial,
                                                const float* __restrict__ cb,
                                                const float* __restrict__ bias,
                                                float* __restrict__ out) {
  const int b = threadIdx.x;  // 128 threads, 1 block
  float k = 0.0f;
#pragma unroll
  for (int c = 0; c < 16; ++c) k += cb[c] * 0.5f + bias[c];
  float s = 0.0f;
#pragma unroll
  for (int q = 0; q < 8; ++q) s += partial[b * 8 + q];
  out[b] = s * (1.0f / 6750.0f) + k;
}

extern "C" void kernel_launch(void* const* d_in, const int* in_sizes, int n_in,
                              void* d_out, int out_size, void* d_ws, size_t ws_size,
                              hipStream_t stream) {
  const float* x    = (const float*)d_in[0];
  const float* cw   = (const float*)d_in[1];
  const float* cb   = (const float*)d_in[2];
  const float* bias = (const float*)d_in[3];
  float* out = (float*)d_out;

  short* Bp      = (short*)d_ws;                   // 576*16 B = 9216 B
  float* partial = (float*)((char*)d_ws + 32768);  // 1024 floats

  prep_w<<<3, 256, 0, stream>>>(cw, Bp);
  conv_mfma<<<1024, 256, 0, stream>>>(x, Bp, partial);
  finalize<<<1, 128, 0, stream>>>(partial, cb, bias, out);
}